// Round 7
// baseline (416.127 us; speedup 1.0000x reference)
//
#include <hip/hip_runtime.h>

#define TT 128
#define BB 32
#define NN (TT*BB)   // 4096

typedef float f4 __attribute__((ext_vector_type(4)));
typedef float f32x4 __attribute__((ext_vector_type(4)));
typedef short s8 __attribute__((ext_vector_type(8)));
typedef short bf16x8 __attribute__((ext_vector_type(8)));
typedef short s4v __attribute__((ext_vector_type(4)));

__device__ __forceinline__ float bf2f(unsigned short u){
  union{unsigned int i; float f;} x; x.i = ((unsigned int)u)<<16; return x.f;
}
__device__ __forceinline__ unsigned short f2bf(float f){
  union{float ff; unsigned int i;} x; x.ff=f;
  unsigned int r = x.i + 0x7FFFu + ((x.i>>16)&1u);
  return (unsigned short)(r>>16);
}
// NaN-safe fast sigmoid/tanh
__device__ __forceinline__ float fsig(float x){
  return __builtin_amdgcn_rcpf(1.f + __expf(-x));
}
__device__ __forceinline__ float ftanh(float x){
  return 1.f - 2.f*__builtin_amdgcn_rcpf(1.f + __expf(2.f*x));
}
// async global(16B contiguous per lane) -> LDS (wave-uniform base + lane*16)
__device__ __forceinline__ void gload_lds16(const void* g, void* lds){
  __builtin_amdgcn_global_load_lds(
    (const __attribute__((address_space(1))) unsigned int*)g,
    (__attribute__((address_space(3))) unsigned int*)lds, 16, 0, 0);
}

// ================= weight prep =============================================
// w1c[co][kh*8+kw] = W1[co][0][kh][kw]/255   (32x64)
__global__ __launch_bounds__(256) void prep_w1(const float* __restrict__ W1,
    unsigned short* __restrict__ w1c){
  int i = blockIdx.x*256 + threadIdx.x;       // 2048
  w1c[i] = f2bf(W1[i] * (1.f/255.f));
}
// w2c[co][(kh*4+kw)*32+ci] = W2[co][ci][kh][kw]   (64x512)
__global__ __launch_bounds__(256) void prep_w2(const float* __restrict__ W2,
    unsigned short* __restrict__ w2c){
  int i = blockIdx.x*256 + threadIdx.x;       // 32768
  int co = i >> 9; int rem = i & 511; int khw = rem >> 5; int ci = rem & 31;
  w2c[i] = f2bf(W2[(co*32 + ci)*16 + khw]);
}
__global__ __launch_bounds__(256) void prep_w3(const float* __restrict__ W3,
    unsigned short* __restrict__ w3c){
  int i = blockIdx.x*256 + threadIdx.x;       // 36864
  int co = i/576; int rem = i - co*576; int khw = rem >> 6; int ci = rem & 63;
  w3c[i] = f2bf(W3[(co*64 + ci)*9 + khw]);
}
__global__ __launch_bounds__(256) void prep_wfc(const float* __restrict__ Wfc,
    unsigned short* __restrict__ wfcc){
  int i = blockIdx.x*256 + threadIdx.x;       // 1605632
  int nn = i/3136; int rem = i - nn*3136; int sp = rem >> 6; int ci = rem & 63;
  wfcc[i] = f2bf(Wfc[nn*3136 + ci*49 + sp]);
}
__global__ __launch_bounds__(256) void prep_wih(const float* __restrict__ W_ih,
    unsigned short* __restrict__ wihc){
  int i = blockIdx.x*256 + threadIdx.x;       // 262144
  wihc[i] = f2bf(W_ih[i]);
}
__global__ __launch_bounds__(256) void prep_whh(const float* __restrict__ W_hh,
    unsigned short* __restrict__ whhc){
  int i = blockIdx.x*256 + threadIdx.x;       // 65536
  whhc[i] = f2bf(W_hh[i]);
}

// ================= fused conv1+conv2: one block per image ==================
// 4096 blocks x 256 thr (4 waves). LDS: image bf16, z1 bf16, w1, w2 (113 KB).
// conv1: M=400(25 t), N=32(2 t), K=64(2 steps) -> z1 LDS [400][34 pad]
// conv2: M=81(6 t, guarded), N=64 (wave w = N-tile w), K=512(16 steps) -> z2 global
__global__ __launch_bounds__(256) void conv12_k(
    const float* __restrict__ x,
    const unsigned short* __restrict__ w1c, const float* __restrict__ b1,
    const unsigned short* __restrict__ w2c, const float* __restrict__ b2,
    unsigned short* __restrict__ z2){
  __shared__ unsigned short xI[84*88];     // 14784 B
  __shared__ unsigned short z1[400*34];    // 27200 B
  __shared__ unsigned short w1L[32*68];    //  4352 B
  __shared__ unsigned short w2L[64*520];   // 66560 B
  int t = threadIdx.x;
  int n = blockIdx.x;
  int w = t >> 6, l = t & 63;
  int lr = l & 15, lg = l >> 4;

  // ---- stage w1 (2048 elems): thread t -> row t>>3, cols (t&7)*8..+7
  {
    bf16x8 v = *(const bf16x8*)&w1c[t*8];
    *(bf16x8*)&w1L[(t>>3)*68 + (t&7)*8] = v;
  }
  // ---- stage w2 (32768 elems): thread t -> row t>>2, quarter (t&3), 16x8
  {
    int row = t >> 2, c0 = (t & 3)*128;
    #pragma unroll
    for(int j=0;j<16;j++){
      bf16x8 v = *(const bf16x8*)&w2c[row*512 + c0 + j*8];
      *(bf16x8*)&w2L[row*520 + c0 + j*8] = v;
    }
  }
  // ---- stage image (1764 f4 = 7056 f32), cvt bf16
  {
    const float* xb = x + (size_t)n*7056;
    #pragma unroll
    for(int j=0;j<7;j++){
      int idx = t + 256*j;
      if(idx < 1764){
        f4 v = *(const f4*)(xb + idx*4);
        s4v p;
        #pragma unroll
        for(int e=0;e<4;e++) p[e] = (short)f2bf(v[e]);
        int row = idx/21, col = (idx - row*21)*4;   // 84 = 21*4
        *(s4v*)&xI[row*88 + col] = p;
      }
    }
  }
  __syncthreads();

  // ---- conv1 ----
  bf16x8 bf1[2][2];   // [nt][s]
  #pragma unroll
  for(int nt=0;nt<2;nt++)
    #pragma unroll
    for(int s=0;s<2;s++)
      bf1[nt][s] = *(const bf16x8*)&w1L[(nt*16+lr)*68 + s*32 + lg*8];
  for(int mt=w; mt<25; mt+=4){
    int p = mt*16 + lr;
    int oh = p/20, ow = p - oh*20;
    // A-frag: k = s*32 + lg*8 + j ; kh = s*4+lg, kw = j (contig 8)
    bf16x8 a0 = *(const bf16x8*)&xI[(oh*4 + lg    )*88 + ow*4];
    bf16x8 a1 = *(const bf16x8*)&xI[(oh*4 + 4 + lg)*88 + ow*4];
    f32x4 acc[2] = {};
    acc[0] = __builtin_amdgcn_mfma_f32_16x16x32_bf16(a0, bf1[0][0], acc[0], 0,0,0);
    acc[0] = __builtin_amdgcn_mfma_f32_16x16x32_bf16(a1, bf1[0][1], acc[0], 0,0,0);
    acc[1] = __builtin_amdgcn_mfma_f32_16x16x32_bf16(a0, bf1[1][0], acc[1], 0,0,0);
    acc[1] = __builtin_amdgcn_mfma_f32_16x16x32_bf16(a1, bf1[1][1], acc[1], 0,0,0);
    #pragma unroll
    for(int nt=0;nt<2;nt++){
      int ch = nt*16 + lr;
      float bb = b1[ch];
      #pragma unroll
      for(int reg=0;reg<4;reg++){
        int pp = mt*16 + lg*4 + reg;
        float v = acc[nt][reg] + bb; v = v>0.f ? v : 0.f;
        z1[pp*34 + ch] = f2bf(v);
      }
    }
  }
  __syncthreads();

  // ---- conv2 ----
  int rbase[6];
  #pragma unroll
  for(int mt=0;mt<6;mt++){
    int q = mt*16 + lr; if(q > 80) q = 80;
    int oh = q/9, ow = q - oh*9;
    rbase[mt] = (2*oh)*20 + 2*ow;
  }
  f32x4 acc2[6] = {};
  for(int s=0;s<16;s++){
    int kh = s>>2, kw = s&3;
    bf16x8 bfr = *(const bf16x8*)&w2L[(w*16+lr)*520 + s*32 + lg*8];
    #pragma unroll
    for(int mt=0;mt<6;mt++){
      bf16x8 af = *(const bf16x8*)&z1[(rbase[mt] + kh*20 + kw)*34 + lg*8];
      acc2[mt] = __builtin_amdgcn_mfma_f32_16x16x32_bf16(af, bfr, acc2[mt], 0,0,0);
    }
  }
  {
    int ch = w*16 + lr;
    float bb = b2[ch];
    #pragma unroll
    for(int mt=0;mt<6;mt++)
      #pragma unroll
      for(int reg=0;reg<4;reg++){
        int q = mt*16 + lg*4 + reg;
        if(q < 81){
          float v = acc2[mt][reg] + bb; v = v>0.f ? v : 0.f;
          z2[((size_t)n*81 + q)*64 + ch] = f2bf(v);
        }
      }
  }
}

// ================= unified MFMA GEMM =======================================
// C[M,N] = act(A[M,K]*B[N,K]^T + bias1 (+bias2)); A bf16 (gathered), B bf16 [N][K].
// BM=128, BN=64, BK=32. 256 threads = 4 waves (2x2), wave tile 64x32.
// MODE 0: plain A rows. MODE 2: conv3 implicit (z2 NHWC 9x9x64).
// SWZ: XCD-chunked bm remap (needs gridDim.y % 8 == 0).
template<int MODE, int OUTBF16, int RELU, int SWZ>
__global__ __launch_bounds__(256) void mgemm_k(
    const unsigned short* __restrict__ A, const unsigned short* __restrict__ B,
    const float* __restrict__ bias1, const float* __restrict__ bias2,
    void* __restrict__ Cout, int K, int Nld, int nout){
  __shared__ unsigned short As[128*40];
  __shared__ unsigned short Bs[64*40];
  int t = threadIdx.x;
  int bm = blockIdx.y, bn = blockIdx.x;
  if(SWZ){
    int cpx = gridDim.y >> 3;
    bm = (bm & 7)*cpx + (bm >> 3);
  }
  int arow = t >> 1, ahalf = t & 1;
  int gm = bm*128 + arow;
  const unsigned short* abase;
  if(MODE == 0){
    abase = A + (size_t)gm*K + ahalf*16;
  } else {
    int n = gm/49; int r = gm - n*49; int oh = r/7; int ow = r - oh*7;
    abase = A + (((size_t)n*9 + oh)*9 + ow)*64 + ahalf*16;
  }
  int brow = t >> 2, bq = t & 3;
  const unsigned short* bbase = B + (size_t)(bn*64 + brow)*K + bq*8;
  int l = t & 63, w = t >> 6;
  int wr = w >> 1, wc = w & 1;
  int lr = l & 15, lk = (l >> 4)*8;
  f32x4 acc[4][2] = {};
  int nsteps = K >> 5;
  for(int s=0; s<nsteps; s++){
    const unsigned short* src;
    if(MODE == 0){
      src = abase + s*32;
    } else {
      int khw = s >> 1; int kh = khw/3; int kw = khw - kh*3;
      src = abase + (kh*9 + kw)*64 + (s & 1)*32;
    }
    bf16x8 a0 = *(const bf16x8*)src;
    bf16x8 a1 = *(const bf16x8*)(src + 8);
    *(bf16x8*)&As[arow*40 + ahalf*16] = a0;
    *(bf16x8*)&As[arow*40 + ahalf*16 + 8] = a1;
    bf16x8 bv = *(const bf16x8*)(bbase + s*32);
    *(bf16x8*)&Bs[brow*40 + bq*8] = bv;
    __syncthreads();
    bf16x8 af[4];
    #pragma unroll
    for(int mf=0; mf<4; mf++)
      af[mf] = *(const bf16x8*)&As[(wr*64 + mf*16 + lr)*40 + lk];
    bf16x8 b0 = *(const bf16x8*)&Bs[(wc*32 + lr)*40 + lk];
    bf16x8 b1 = *(const bf16x8*)&Bs[(wc*32 + 16 + lr)*40 + lk];
    #pragma unroll
    for(int mf=0; mf<4; mf++){
      acc[mf][0] = __builtin_amdgcn_mfma_f32_16x16x32_bf16(af[mf], b0, acc[mf][0], 0, 0, 0);
      acc[mf][1] = __builtin_amdgcn_mfma_f32_16x16x32_bf16(af[mf], b1, acc[mf][1], 0, 0, 0);
    }
    __syncthreads();
  }
  #pragma unroll
  for(int nf=0; nf<2; nf++){
    int gcol = bn*64 + wc*32 + nf*16 + lr;
    if(gcol >= nout) continue;
    float bb = bias1[gcol] + (bias2 ? bias2[gcol] : 0.f);
    #pragma unroll
    for(int mf=0; mf<4; mf++){
      #pragma unroll
      for(int reg=0; reg<4; reg++){
        int grow = bm*128 + wr*64 + mf*16 + (l>>4)*4 + reg;
        float v = acc[mf][nf][reg] + bb;
        if(RELU) v = v>0.f ? v : 0.f;
        if(OUTBF16) ((unsigned short*)Cout)[(size_t)grow*Nld + gcol] = f2bf(v);
        else        ((float*)Cout)[(size_t)grow*Nld + gcol] = v;
      }
    }
  }
}

// ================= LSTM scan v3: 8 blocks x 4 batch ========================
// gW layout [g][u16][b4]: scatter 2-way (free), gather = 4 b32 at g*64+l.
__global__ __launch_bounds__(512) void lstm_v3_k(
    const float* __restrict__ gx,   // [4096][512] f32
    const float* __restrict__ done,
    const float* __restrict__ h0, const float* __restrict__ c0,
    const unsigned short* __restrict__ whhc,
    float* __restrict__ hs, float* __restrict__ out_hT, float* __restrict__ out_cT){
  __shared__ float mask_lds[TT*4];
  __shared__ unsigned short hA[2][4][136];
  __shared__ __align__(16) float gxS[3][4][520];
  __shared__ __align__(16) float gW[8][256];     // per-wave [g4][u16][b4]
  int tid = threadIdx.x;
  int B0 = blockIdx.x * 4;
  int w = tid >> 6, l = tid & 63;
  int lr = l & 15, lg = l >> 4;
  int cu = 16*w + (l >> 2);
  int cb = l & 3;
  int drow = w >> 1, dhalf = w & 1;

  bf16x8 wA[4][4];
  #pragma unroll
  for(int g=0; g<4; g++)
    #pragma unroll
    for(int kt=0; kt<4; kt++)
      wA[g][kt] = *(const bf16x8*)&whhc[(size_t)(g*128 + 16*w + lr)*128 + kt*32 + lg*8];

  {
    int tt = tid >> 2, bb = tid & 3;
    mask_lds[tid] = 1.f - done[tt*32 + B0 + bb];
  }
  float cv = c0[(size_t)(B0+cb)*128 + cu];
  float hv0 = h0[(size_t)(B0+cb)*128 + cu];
  float hout = 0.f;
  {
    float m0 = 1.f - done[0*BB + B0 + cb];
    hA[0][cb][cu] = f2bf(hv0 * m0);
  }
  #pragma unroll
  for(int sl=0; sl<2; sl++)
    gload_lds16(gx + ((size_t)(sl*32 + B0 + drow))*512 + dhalf*256 + l*4,
                &gxS[sl][drow][dhalf*256]);
  __syncthreads();

  int slot = 0;
  for(int t=0; t<TT; t++){
    int cur = t & 1;
    {
      int ts = (t+2 < TT) ? t+2 : TT-1;
      int s2 = (slot >= 1) ? slot-1 : 2;
      gload_lds16(gx + ((size_t)(ts*32 + B0 + drow))*512 + dhalf*256 + l*4,
                  &gxS[s2][drow][dhalf*256]);
    }
    bf16x8 hF[4];
    #pragma unroll
    for(int kt=0; kt<4; kt++)
      hF[kt] = *(const bf16x8*)&hA[cur][lr & 3][kt*32 + lg*8];
    f32x4 acc[4] = {};
    #pragma unroll
    for(int kt=0; kt<4; kt++)
      #pragma unroll
      for(int g=0; g<4; g++)
        acc[g] = __builtin_amdgcn_mfma_f32_16x16x32_bf16(wA[g][kt], hF[kt], acc[g], 0, 0, 0);
    if(lr < 4){
      #pragma unroll
      for(int g=0; g<4; g++)
        #pragma unroll
        for(int r=0; r<4; r++)
          gW[w][g*64 + (lg*4 + r)*4 + lr] = acc[g][r];
    }
    asm volatile("s_waitcnt lgkmcnt(0)" ::: "memory");
    float g0 = gW[w][      l];
    float g1 = gW[w][ 64 + l];
    float g2 = gW[w][128 + l];
    float g3 = gW[w][192 + l];
    float gx0 = gxS[slot][cb][      cu];
    float gx1 = gxS[slot][cb][128 + cu];
    float gx2 = gxS[slot][cb][256 + cu];
    float gx3 = gxS[slot][cb][384 + cu];
    float m  = mask_lds[t*4 + cb];
    float mn = (t < TT-1) ? mask_lds[(t+1)*4 + cb] : 1.f;
    float iv = fsig (g0 + gx0);
    float fv = fsig (g1 + gx1);
    float gv = ftanh(g2 + gx2);
    float ov = fsig (g3 + gx3);
    float cn = fv*(cv*m) + iv*gv;
    float hn = ov*ftanh(cn);
    cv = cn; hout = hn;
    hs[((size_t)t*BB + B0 + cb)*128 + cu] = hn;
    hA[cur^1][cb][cu] = f2bf(hn * mn);
    asm volatile("s_waitcnt vmcnt(3) lgkmcnt(0)" ::: "memory");
    __builtin_amdgcn_s_barrier();
    slot = (slot >= 2) ? 0 : slot+1;
  }
  out_hT[(size_t)(B0+cb)*128 + cu] = hout;
  out_cT[(size_t)(B0+cb)*128 + cu] = cv;
}

// ================= heads ===================================================
__global__ __launch_bounds__(256) void heads_k(const float* __restrict__ hs,
    const float* __restrict__ Wa, const float* __restrict__ ba,
    const float* __restrict__ Wc, const float* __restrict__ bc,
    float* __restrict__ out){
  int gid = blockIdx.x*256 + threadIdx.x;  // 4096*7
  int n = gid/7, a = gid - n*7;
  const float* w = (a<6) ? (Wa + a*128) : Wc;
  float bias = (a<6) ? ba[a] : bc[0];
  const float* h = hs + (size_t)n*128;
  float acc = 0.f;
  #pragma unroll
  for(int k=0;k<32;k++){
    f4 hv = *(const f4*)(h + k*4);
    f4 wv = *(const f4*)(w + k*4);
    acc += hv[0]*wv[0]+hv[1]*wv[1]+hv[2]*wv[2]+hv[3]*wv[3];
  }
  float v = acc + bias;
  if(a<6) out[(size_t)n*6 + a] = v;
  else    out[24576 + n] = v;
}

extern "C" void kernel_launch(void* const* d_in, const int* in_sizes, int n_in,
                              void* d_out, int out_size, void* d_ws, size_t ws_size,
                              hipStream_t stream){
  const float* x    = (const float*)d_in[0];
  const float* done = (const float*)d_in[1];
  const float* h0   = (const float*)d_in[2];
  const float* c0   = (const float*)d_in[3];
  const float* W1   = (const float*)d_in[4];
  const float* b1   = (const float*)d_in[5];
  const float* W2   = (const float*)d_in[6];
  const float* b2   = (const float*)d_in[7];
  const float* W3   = (const float*)d_in[8];
  const float* b3   = (const float*)d_in[9];
  const float* Wfc  = (const float*)d_in[10];
  const float* bfc  = (const float*)d_in[11];
  const float* W_ih = (const float*)d_in[12];
  const float* W_hh = (const float*)d_in[13];
  const float* b_ih = (const float*)d_in[14];
  const float* b_hh = (const float*)d_in[15];
  const float* Wa   = (const float*)d_in[16];
  const float* ba   = (const float*)d_in[17];
  const float* Wc   = (const float*)d_in[18];
  const float* bc   = (const float*)d_in[19];
  float* out = (float*)d_out;

  char* ws = (char*)d_ws;
  // region plan (bytes):
  //  z2   [0, 42467328)            (n,81,64) bf16   [conv12 -> conv3]
  //  z3   [42467328, 68157440)     (n,49,64) bf16   [conv3 -> FC]
  //  hid  [68157440, 72351744)     (4096,512) bf16
  //  gx   [72351744, 80740352)     (4096,512) f32
  //  hs   [80740352, 82837504)     (4096,128) f32
  //  w1c  [82837504, +8192) w2c +64K w3c +72K wfcc +3136K wihc +512K whhc +128K
  unsigned short* z2   = (unsigned short*)(ws + 0);
  unsigned short* z3   = (unsigned short*)(ws + 42467328);
  unsigned short* hid  = (unsigned short*)(ws + 68157440);
  float* gx            = (float*)(ws + 72351744);
  float* hs            = (float*)(ws + 80740352);
  unsigned short* w1c  = (unsigned short*)(ws + 82837504);
  unsigned short* w2c  = (unsigned short*)(ws + 82845696);
  unsigned short* w3c  = (unsigned short*)(ws + 82911232);
  unsigned short* wfcc = (unsigned short*)(ws + 82984960);
  unsigned short* wihc = (unsigned short*)(ws + 86196224);
  unsigned short* whhc = (unsigned short*)(ws + 86720512);

  prep_w1 <<<8,   256, 0, stream>>>(W1, w1c);
  prep_w2 <<<128, 256, 0, stream>>>(W2, w2c);
  prep_w3 <<<144, 256, 0, stream>>>(W3, w3c);
  prep_wfc<<<6272,256, 0, stream>>>(Wfc, wfcc);
  prep_wih<<<1024,256, 0, stream>>>(W_ih, wihc);
  prep_whh<<<256, 256, 0, stream>>>(W_hh, whhc);

  // fused conv1+conv2: 1 block per image
  conv12_k<<<4096,256,0,stream>>>(x, w1c, b1, w2c, b2, z2);
  // conv3: M=4096*49, N=64, K=576 (XCD-swizzled: 1568 % 8 == 0)
  mgemm_k<2,1,1,1><<<dim3(1,1568),256,0,stream>>>(z2, w3c, b3, nullptr, z3, 576, 64, 64);
  // FC: M=4096, N=512, K=3136 -> hid bf16 relu
  mgemm_k<0,1,1,0><<<dim3(8,32),256,0,stream>>>(z3, wfcc, bfc, nullptr, hid, 3136, 512, 512);
  // gates: M=4096, N=512, K=512 -> gx f32 row-major
  mgemm_k<0,0,0,0><<<dim3(8,32),256,0,stream>>>(hid, wihc, b_ih, b_hh, gx, 512, 512, 512);

  lstm_v3_k<<<8,512,0,stream>>>(gx, done, h0, c0, whhc, hs, out+28672, out+32768);
  heads_k<<<112,256,0,stream>>>(hs, Wa, ba, Wc, bc, out);
}

// Round 8
// 305.118 us; speedup vs baseline: 1.3638x; 1.3638x over previous
//
#include <hip/hip_runtime.h>

#define TT 128
#define BB 32
#define NN (TT*BB)   // 4096

typedef float f4 __attribute__((ext_vector_type(4)));
typedef float f32x4 __attribute__((ext_vector_type(4)));
typedef short s8 __attribute__((ext_vector_type(8)));
typedef short bf16x8 __attribute__((ext_vector_type(8)));
typedef short s4v __attribute__((ext_vector_type(4)));

__device__ __forceinline__ float bf2f(unsigned short u){
  union{unsigned int i; float f;} x; x.i = ((unsigned int)u)<<16; return x.f;
}
__device__ __forceinline__ unsigned short f2bf(float f){
  union{float ff; unsigned int i;} x; x.ff=f;
  unsigned int r = x.i + 0x7FFFu + ((x.i>>16)&1u);
  return (unsigned short)(r>>16);
}
// NaN-safe fast sigmoid/tanh
__device__ __forceinline__ float fsig(float x){
  return __builtin_amdgcn_rcpf(1.f + __expf(-x));
}
__device__ __forceinline__ float ftanh(float x){
  return 1.f - 2.f*__builtin_amdgcn_rcpf(1.f + __expf(2.f*x));
}
// async global(16B contiguous per lane) -> LDS (wave-uniform base + lane*16)
__device__ __forceinline__ void gload_lds16(const void* g, void* lds){
  __builtin_amdgcn_global_load_lds(
    (const __attribute__((address_space(1))) unsigned int*)g,
    (__attribute__((address_space(3))) unsigned int*)lds, 16, 0, 0);
}

// ================= weight prep =============================================
// w1c[co][kh*8+kw] = W1[co][0][kh][kw]/255   (32x64)
__global__ __launch_bounds__(256) void prep_w1(const float* __restrict__ W1,
    unsigned short* __restrict__ w1c){
  int i = blockIdx.x*256 + threadIdx.x;       // 2048
  w1c[i] = f2bf(W1[i] * (1.f/255.f));
}
// w2c[co][(kh*4+kw)*32+ci] = W2[co][ci][kh][kw]   (64x512)
__global__ __launch_bounds__(256) void prep_w2(const float* __restrict__ W2,
    unsigned short* __restrict__ w2c){
  int i = blockIdx.x*256 + threadIdx.x;       // 32768
  int co = i >> 9; int rem = i & 511; int khw = rem >> 5; int ci = rem & 31;
  w2c[i] = f2bf(W2[(co*32 + ci)*16 + khw]);
}
__global__ __launch_bounds__(256) void prep_w3(const float* __restrict__ W3,
    unsigned short* __restrict__ w3c){
  int i = blockIdx.x*256 + threadIdx.x;       // 36864
  int co = i/576; int rem = i - co*576; int khw = rem >> 6; int ci = rem & 63;
  w3c[i] = f2bf(W3[(co*64 + ci)*9 + khw]);
}
__global__ __launch_bounds__(256) void prep_wfc(const float* __restrict__ Wfc,
    unsigned short* __restrict__ wfcc){
  int i = blockIdx.x*256 + threadIdx.x;       // 1605632
  int nn = i/3136; int rem = i - nn*3136; int sp = rem >> 6; int ci = rem & 63;
  wfcc[i] = f2bf(Wfc[nn*3136 + ci*49 + sp]);
}
__global__ __launch_bounds__(256) void prep_wih(const float* __restrict__ W_ih,
    unsigned short* __restrict__ wihc){
  int i = blockIdx.x*256 + threadIdx.x;       // 262144
  wihc[i] = f2bf(W_ih[i]);
}
__global__ __launch_bounds__(256) void prep_whh(const float* __restrict__ W_hh,
    unsigned short* __restrict__ whhc){
  int i = blockIdx.x*256 + threadIdx.x;       // 65536
  whhc[i] = f2bf(W_hh[i]);
}

// ================= fused conv1+conv2 v2: one block per image ===============
// 4096 blocks x 256 thr (4 waves). LDS 44.7 KB -> 3 blocks/CU.
// z1 layout: [p>>1][(p&1)*32 + ch] bf16, 128-B rows, T2 XOR swizzle
//   byte_in_row ^= ((row&7)<<4). conv2 read: lanes vary row (pixel/2), fixed
//   col-slice -> conflict-free (m201 regime). conv1 writes D[ch][pixel]
//   (swapped MFMA operands) -> one b64 write per (mt,nt) through same swizzle.
// w2 B-frags read from GLOBAL (L2-broadcast), 2-deep register prefetch.
__global__ __launch_bounds__(256) void conv12_k(
    const float* __restrict__ x,
    const unsigned short* __restrict__ w1c, const float* __restrict__ b1,
    const unsigned short* __restrict__ w2c, const float* __restrict__ b2,
    unsigned short* __restrict__ z2){
  __shared__ unsigned short xI[84*88];      // 14784 B
  __shared__ unsigned short z1s[200*64];    // 25600 B (swizzled)
  __shared__ unsigned short w1L[32*68];     //  4352 B
  int t = threadIdx.x;
  int n = blockIdx.x;
  int w = t >> 6, l = t & 63;
  int lr = l & 15, lg = l >> 4;

  // ---- stage w1 (2048 elems)
  {
    bf16x8 v = *(const bf16x8*)&w1c[t*8];
    *(bf16x8*)&w1L[(t>>3)*68 + (t&7)*8] = v;
  }
  // ---- stage image (1764 f4), cvt bf16
  {
    const float* xb = x + (size_t)n*7056;
    #pragma unroll
    for(int j=0;j<7;j++){
      int idx = t + 256*j;
      if(idx < 1764){
        f4 v = *(const f4*)(xb + idx*4);
        s4v p;
        #pragma unroll
        for(int e=0;e<4;e++) p[e] = (short)f2bf(v[e]);
        int row = idx/21, col = (idx - row*21)*4;   // 84 = 21*4
        *(s4v*)&xI[row*88 + col] = p;
      }
    }
  }
  __syncthreads();

  // ---- conv1: D[ch][pixel] = mfma(w1_frag, x_frag) ----
  bf16x8 wf1[2][2];   // [nt][s]
  #pragma unroll
  for(int nt=0;nt<2;nt++)
    #pragma unroll
    for(int s=0;s<2;s++)
      wf1[nt][s] = *(const bf16x8*)&w1L[(nt*16+lr)*68 + s*32 + lg*8];
  f4 b1v[2];
  b1v[0] = *(const f4*)&b1[lg*4];
  b1v[1] = *(const f4*)&b1[16 + lg*4];
  for(int mt=w; mt<25; mt+=4){
    int p = mt*16 + lr;
    int oh = p/20, ow = p - oh*20;
    // x B-frag: col=pixel(lr), k = s*32 + lg*8 + j ; kh = s*4+lg, kw = j
    bf16x8 a0 = *(const bf16x8*)&xI[(oh*4 + lg    )*88 + ow*4];
    bf16x8 a1 = *(const bf16x8*)&xI[(oh*4 + 4 + lg)*88 + ow*4];
    f32x4 acc[2] = {};
    acc[0] = __builtin_amdgcn_mfma_f32_16x16x32_bf16(wf1[0][0], a0, acc[0], 0,0,0);
    acc[0] = __builtin_amdgcn_mfma_f32_16x16x32_bf16(wf1[0][1], a1, acc[0], 0,0,0);
    acc[1] = __builtin_amdgcn_mfma_f32_16x16x32_bf16(wf1[1][0], a0, acc[1], 0,0,0);
    acc[1] = __builtin_amdgcn_mfma_f32_16x16x32_bf16(wf1[1][1], a1, acc[1], 0,0,0);
    // write: pixel p' = mt*16 + lr (this lane's col), ch = nt*16 + lg*4 + reg
    int row = p >> 1;
    int par = (p & 1) << 6;
    int swz = (row & 7) << 4;
    #pragma unroll
    for(int nt=0;nt<2;nt++){
      s4v hp;
      #pragma unroll
      for(int reg=0;reg<4;reg++){
        float v = acc[nt][reg] + b1v[nt][reg];
        v = v>0.f ? v : 0.f;
        hp[reg] = (short)f2bf(v);
      }
      int byteoff = (par + (nt*16 + lg*4)*2) ^ swz;
      *(s4v*)((char*)z1s + row*128 + byteoff) = hp;
    }
  }
  __syncthreads();

  // ---- conv2: acc2[pixel-block] = sum_s mfma(z1_frag, w2_frag) ----
  int rbase[6];
  #pragma unroll
  for(int mt=0;mt<6;mt++){
    int q = mt*16 + lr; if(q > 80) q = 80;
    int oh = q/9, ow = q - oh*9;
    rbase[mt] = (2*oh)*20 + 2*ow;
  }
  const unsigned short* wrow = w2c + (size_t)(w*16 + lr)*512 + lg*8;
  bf16x8 bq0 = *(const bf16x8*)(wrow);
  bf16x8 bq1 = *(const bf16x8*)(wrow + 32);
  f32x4 acc2[6] = {};
  #pragma unroll
  for(int s=0;s<16;s++){
    bf16x8 bcur = (s & 1) ? bq1 : bq0;
    if(s+2 < 16){
      bf16x8 bn = *(const bf16x8*)(wrow + (s+2)*32);
      if(s & 1) bq1 = bn; else bq0 = bn;
    }
    int kh = s>>2, kw = s&3;
    int swzbase = ((kw & 1) << 6) + (lg << 4);
    #pragma unroll
    for(int mt=0;mt<6;mt++){
      int p = rbase[mt] + kh*20 + kw;
      int row = p >> 1;
      int byteoff = swzbase ^ ((row & 7) << 4);
      bf16x8 af = *(const bf16x8*)((const char*)z1s + row*128 + byteoff);
      acc2[mt] = __builtin_amdgcn_mfma_f32_16x16x32_bf16(af, bcur, acc2[mt], 0,0,0);
    }
  }
  {
    int ch = w*16 + lr;
    float bb = b2[ch];
    #pragma unroll
    for(int mt=0;mt<6;mt++)
      #pragma unroll
      for(int reg=0;reg<4;reg++){
        int q = mt*16 + lg*4 + reg;
        if(q < 81){
          float v = acc2[mt][reg] + bb; v = v>0.f ? v : 0.f;
          z2[((size_t)n*81 + q)*64 + ch] = f2bf(v);
        }
      }
  }
}

// ================= unified MFMA GEMM =======================================
// C[M,N] = act(A[M,K]*B[N,K]^T + bias1 (+bias2)); A bf16 (gathered), B bf16 [N][K].
// BM=128, BN=64, BK=32. 256 threads = 4 waves (2x2), wave tile 64x32.
// MODE 0: plain A rows. MODE 2: conv3 implicit (z2 NHWC 9x9x64).
// SWZ: XCD-chunked bm remap (needs gridDim.y % 8 == 0).
template<int MODE, int OUTBF16, int RELU, int SWZ>
__global__ __launch_bounds__(256) void mgemm_k(
    const unsigned short* __restrict__ A, const unsigned short* __restrict__ B,
    const float* __restrict__ bias1, const float* __restrict__ bias2,
    void* __restrict__ Cout, int K, int Nld, int nout){
  __shared__ unsigned short As[128*40];
  __shared__ unsigned short Bs[64*40];
  int t = threadIdx.x;
  int bm = blockIdx.y, bn = blockIdx.x;
  if(SWZ){
    int cpx = gridDim.y >> 3;
    bm = (bm & 7)*cpx + (bm >> 3);
  }
  int arow = t >> 1, ahalf = t & 1;
  int gm = bm*128 + arow;
  const unsigned short* abase;
  if(MODE == 0){
    abase = A + (size_t)gm*K + ahalf*16;
  } else {
    int n = gm/49; int r = gm - n*49; int oh = r/7; int ow = r - oh*7;
    abase = A + (((size_t)n*9 + oh)*9 + ow)*64 + ahalf*16;
  }
  int brow = t >> 2, bq = t & 3;
  const unsigned short* bbase = B + (size_t)(bn*64 + brow)*K + bq*8;
  int l = t & 63, w = t >> 6;
  int wr = w >> 1, wc = w & 1;
  int lr = l & 15, lk = (l >> 4)*8;
  f32x4 acc[4][2] = {};
  int nsteps = K >> 5;
  for(int s=0; s<nsteps; s++){
    const unsigned short* src;
    if(MODE == 0){
      src = abase + s*32;
    } else {
      int khw = s >> 1; int kh = khw/3; int kw = khw - kh*3;
      src = abase + (kh*9 + kw)*64 + (s & 1)*32;
    }
    bf16x8 a0 = *(const bf16x8*)src;
    bf16x8 a1 = *(const bf16x8*)(src + 8);
    *(bf16x8*)&As[arow*40 + ahalf*16] = a0;
    *(bf16x8*)&As[arow*40 + ahalf*16 + 8] = a1;
    bf16x8 bv = *(const bf16x8*)(bbase + s*32);
    *(bf16x8*)&Bs[brow*40 + bq*8] = bv;
    __syncthreads();
    bf16x8 af[4];
    #pragma unroll
    for(int mf=0; mf<4; mf++)
      af[mf] = *(const bf16x8*)&As[(wr*64 + mf*16 + lr)*40 + lk];
    bf16x8 b0 = *(const bf16x8*)&Bs[(wc*32 + lr)*40 + lk];
    bf16x8 b1 = *(const bf16x8*)&Bs[(wc*32 + 16 + lr)*40 + lk];
    #pragma unroll
    for(int mf=0; mf<4; mf++){
      acc[mf][0] = __builtin_amdgcn_mfma_f32_16x16x32_bf16(af[mf], b0, acc[mf][0], 0, 0, 0);
      acc[mf][1] = __builtin_amdgcn_mfma_f32_16x16x32_bf16(af[mf], b1, acc[mf][1], 0, 0, 0);
    }
    __syncthreads();
  }
  #pragma unroll
  for(int nf=0; nf<2; nf++){
    int gcol = bn*64 + wc*32 + nf*16 + lr;
    if(gcol >= nout) continue;
    float bb = bias1[gcol] + (bias2 ? bias2[gcol] : 0.f);
    #pragma unroll
    for(int mf=0; mf<4; mf++){
      #pragma unroll
      for(int reg=0; reg<4; reg++){
        int grow = bm*128 + wr*64 + mf*16 + (l>>4)*4 + reg;
        float v = acc[mf][nf][reg] + bb;
        if(RELU) v = v>0.f ? v : 0.f;
        if(OUTBF16) ((unsigned short*)Cout)[(size_t)grow*Nld + gcol] = f2bf(v);
        else        ((float*)Cout)[(size_t)grow*Nld + gcol] = v;
      }
    }
  }
}

// ================= LSTM scan v3: 8 blocks x 4 batch ========================
// gW layout [g][u16][b4]: scatter 2-way (free), gather = 4 b32 at g*64+l.
__global__ __launch_bounds__(512) void lstm_v3_k(
    const float* __restrict__ gx,   // [4096][512] f32
    const float* __restrict__ done,
    const float* __restrict__ h0, const float* __restrict__ c0,
    const unsigned short* __restrict__ whhc,
    float* __restrict__ hs, float* __restrict__ out_hT, float* __restrict__ out_cT){
  __shared__ float mask_lds[TT*4];
  __shared__ unsigned short hA[2][4][136];
  __shared__ __align__(16) float gxS[3][4][520];
  __shared__ __align__(16) float gW[8][256];     // per-wave [g4][u16][b4]
  int tid = threadIdx.x;
  int B0 = blockIdx.x * 4;
  int w = tid >> 6, l = tid & 63;
  int lr = l & 15, lg = l >> 4;
  int cu = 16*w + (l >> 2);
  int cb = l & 3;
  int drow = w >> 1, dhalf = w & 1;

  bf16x8 wA[4][4];
  #pragma unroll
  for(int g=0; g<4; g++)
    #pragma unroll
    for(int kt=0; kt<4; kt++)
      wA[g][kt] = *(const bf16x8*)&whhc[(size_t)(g*128 + 16*w + lr)*128 + kt*32 + lg*8];

  {
    int tt = tid >> 2, bb = tid & 3;
    mask_lds[tid] = 1.f - done[tt*32 + B0 + bb];
  }
  float cv = c0[(size_t)(B0+cb)*128 + cu];
  float hv0 = h0[(size_t)(B0+cb)*128 + cu];
  float hout = 0.f;
  {
    float m0 = 1.f - done[0*BB + B0 + cb];
    hA[0][cb][cu] = f2bf(hv0 * m0);
  }
  #pragma unroll
  for(int sl=0; sl<2; sl++)
    gload_lds16(gx + ((size_t)(sl*32 + B0 + drow))*512 + dhalf*256 + l*4,
                &gxS[sl][drow][dhalf*256]);
  __syncthreads();

  int slot = 0;
  for(int t=0; t<TT; t++){
    int cur = t & 1;
    {
      int ts = (t+2 < TT) ? t+2 : TT-1;
      int s2 = (slot >= 1) ? slot-1 : 2;
      gload_lds16(gx + ((size_t)(ts*32 + B0 + drow))*512 + dhalf*256 + l*4,
                  &gxS[s2][drow][dhalf*256]);
    }
    bf16x8 hF[4];
    #pragma unroll
    for(int kt=0; kt<4; kt++)
      hF[kt] = *(const bf16x8*)&hA[cur][lr & 3][kt*32 + lg*8];
    f32x4 acc[4] = {};
    #pragma unroll
    for(int kt=0; kt<4; kt++)
      #pragma unroll
      for(int g=0; g<4; g++)
        acc[g] = __builtin_amdgcn_mfma_f32_16x16x32_bf16(wA[g][kt], hF[kt], acc[g], 0, 0, 0);
    if(lr < 4){
      #pragma unroll
      for(int g=0; g<4; g++)
        #pragma unroll
        for(int r=0; r<4; r++)
          gW[w][g*64 + (lg*4 + r)*4 + lr] = acc[g][r];
    }
    asm volatile("s_waitcnt lgkmcnt(0)" ::: "memory");
    float g0 = gW[w][      l];
    float g1 = gW[w][ 64 + l];
    float g2 = gW[w][128 + l];
    float g3 = gW[w][192 + l];
    float gx0 = gxS[slot][cb][      cu];
    float gx1 = gxS[slot][cb][128 + cu];
    float gx2 = gxS[slot][cb][256 + cu];
    float gx3 = gxS[slot][cb][384 + cu];
    float m  = mask_lds[t*4 + cb];
    float mn = (t < TT-1) ? mask_lds[(t+1)*4 + cb] : 1.f;
    float iv = fsig (g0 + gx0);
    float fv = fsig (g1 + gx1);
    float gv = ftanh(g2 + gx2);
    float ov = fsig (g3 + gx3);
    float cn = fv*(cv*m) + iv*gv;
    float hn = ov*ftanh(cn);
    cv = cn; hout = hn;
    hs[((size_t)t*BB + B0 + cb)*128 + cu] = hn;
    hA[cur^1][cb][cu] = f2bf(hn * mn);
    asm volatile("s_waitcnt vmcnt(3) lgkmcnt(0)" ::: "memory");
    __builtin_amdgcn_s_barrier();
    slot = (slot >= 2) ? 0 : slot+1;
  }
  out_hT[(size_t)(B0+cb)*128 + cu] = hout;
  out_cT[(size_t)(B0+cb)*128 + cu] = cv;
}

// ================= heads ===================================================
__global__ __launch_bounds__(256) void heads_k(const float* __restrict__ hs,
    const float* __restrict__ Wa, const float* __restrict__ ba,
    const float* __restrict__ Wc, const float* __restrict__ bc,
    float* __restrict__ out){
  int gid = blockIdx.x*256 + threadIdx.x;  // 4096*7
  int n = gid/7, a = gid - n*7;
  const float* w = (a<6) ? (Wa + a*128) : Wc;
  float bias = (a<6) ? ba[a] : bc[0];
  const float* h = hs + (size_t)n*128;
  float acc = 0.f;
  #pragma unroll
  for(int k=0;k<32;k++){
    f4 hv = *(const f4*)(h + k*4);
    f4 wv = *(const f4*)(w + k*4);
    acc += hv[0]*wv[0]+hv[1]*wv[1]+hv[2]*wv[2]+hv[3]*wv[3];
  }
  float v = acc + bias;
  if(a<6) out[(size_t)n*6 + a] = v;
  else    out[24576 + n] = v;
}

extern "C" void kernel_launch(void* const* d_in, const int* in_sizes, int n_in,
                              void* d_out, int out_size, void* d_ws, size_t ws_size,
                              hipStream_t stream){
  const float* x    = (const float*)d_in[0];
  const float* done = (const float*)d_in[1];
  const float* h0   = (const float*)d_in[2];
  const float* c0   = (const float*)d_in[3];
  const float* W1   = (const float*)d_in[4];
  const float* b1   = (const float*)d_in[5];
  const float* W2   = (const float*)d_in[6];
  const float* b2   = (const float*)d_in[7];
  const float* W3   = (const float*)d_in[8];
  const float* b3   = (const float*)d_in[9];
  const float* Wfc  = (const float*)d_in[10];
  const float* bfc  = (const float*)d_in[11];
  const float* W_ih = (const float*)d_in[12];
  const float* W_hh = (const float*)d_in[13];
  const float* b_ih = (const float*)d_in[14];
  const float* b_hh = (const float*)d_in[15];
  const float* Wa   = (const float*)d_in[16];
  const float* ba   = (const float*)d_in[17];
  const float* Wc   = (const float*)d_in[18];
  const float* bc   = (const float*)d_in[19];
  float* out = (float*)d_out;

  char* ws = (char*)d_ws;
  // region plan (bytes):
  //  z2   [0, 42467328)            (n,81,64) bf16   [conv12 -> conv3]
  //  z3   [42467328, 68157440)     (n,49,64) bf16   [conv3 -> FC]
  //  hid  [68157440, 72351744)     (4096,512) bf16
  //  gx   [72351744, 80740352)     (4096,512) f32
  //  hs   [80740352, 82837504)     (4096,128) f32
  //  w1c  [82837504, +8192) w2c +64K w3c +72K wfcc +3136K wihc +512K whhc +128K
  unsigned short* z2   = (unsigned short*)(ws + 0);
  unsigned short* z3   = (unsigned short*)(ws + 42467328);
  unsigned short* hid  = (unsigned short*)(ws + 68157440);
  float* gx            = (float*)(ws + 72351744);
  float* hs            = (float*)(ws + 80740352);
  unsigned short* w1c  = (unsigned short*)(ws + 82837504);
  unsigned short* w2c  = (unsigned short*)(ws + 82845696);
  unsigned short* w3c  = (unsigned short*)(ws + 82911232);
  unsigned short* wfcc = (unsigned short*)(ws + 82984960);
  unsigned short* wihc = (unsigned short*)(ws + 86196224);
  unsigned short* whhc = (unsigned short*)(ws + 86720512);

  prep_w1 <<<8,   256, 0, stream>>>(W1, w1c);
  prep_w2 <<<128, 256, 0, stream>>>(W2, w2c);
  prep_w3 <<<144, 256, 0, stream>>>(W3, w3c);
  prep_wfc<<<6272,256, 0, stream>>>(Wfc, wfcc);
  prep_wih<<<1024,256, 0, stream>>>(W_ih, wihc);
  prep_whh<<<256, 256, 0, stream>>>(W_hh, whhc);

  // fused conv1+conv2 v2: 1 block per image
  conv12_k<<<4096,256,0,stream>>>(x, w1c, b1, w2c, b2, z2);
  // conv3: M=4096*49, N=64, K=576 (XCD-swizzled: 1568 % 8 == 0)
  mgemm_k<2,1,1,1><<<dim3(1,1568),256,0,stream>>>(z2, w3c, b3, nullptr, z3, 576, 64, 64);
  // FC: M=4096, N=512, K=3136 -> hid bf16 relu
  mgemm_k<0,1,1,0><<<dim3(8,32),256,0,stream>>>(z3, wfcc, bfc, nullptr, hid, 3136, 512, 512);
  // gates: M=4096, N=512, K=512 -> gx f32 row-major
  mgemm_k<0,0,0,0><<<dim3(8,32),256,0,stream>>>(hid, wihc, b_ih, b_hh, gx, 512, 512, 512);

  lstm_v3_k<<<8,512,0,stream>>>(gx, done, h0, c0, whhc, hs, out+28672, out+32768);
  heads_k<<<112,256,0,stream>>>(hs, Wa, ba, Wc, bc, out);
}